// Round 12
// baseline (100.259 us; speedup 1.0000x reference)
//
#include <hip/hip_runtime.h>
#include <hip/hip_fp16.h>
#include <stdint.h>

#define Nn 2048
#define Ff 1024
#define Mm 128
#define Cc 100
#define Ss 32
#define NM (Nn * Mm)
#define ELS 132
#define SCP 128          // table row stride in halfs
#define TOFF 16416       // em2 offset in halfs (byte 32832 == 64 mod 128 -> +4 bank-quad phase)
#define ESC 0.015625f          // 2^-6 scale on E
#define ESCLOG 4.15888308336f  // 6*ln2

typedef short bf8 __attribute__((ext_vector_type(8)));
typedef float f32x4 __attribute__((ext_vector_type(4)));

__device__ __forceinline__ float qsum4(float x) {
  int a = __builtin_amdgcn_update_dpp(0, __builtin_bit_cast(int, x), 0xB1, 0xF, 0xF, false);
  float xf = x + __builtin_bit_cast(float, a);
  int b = __builtin_amdgcn_update_dpp(0, __builtin_bit_cast(int, xf), 0x4E, 0xF, 0xF, false);
  return xf + __builtin_bit_cast(float, b);
}

// forced v_dot2_f32_f16: r = e.h0*v.h0 + e.h1*v.h1 + c
__device__ __forceinline__ float d2a(uint32_t e, uint32_t v, float c) {
  float r;
  asm("v_dot2_f32_f16 %0, %1, %2, %3" : "=v"(r) : "v"(e), "v"(v), "v"(c));
  return r;
}
// forced v_pk_mul_f16
__device__ __forceinline__ uint32_t pkmul(uint32_t a, uint32_t b) {
  uint32_t r;
  asm("v_pk_mul_f16 %0, %1, %2" : "=v"(r) : "v"(a), "v"(b));
  return r;
}

__device__ __forceinline__ uint32_t hash32(uint32_t chain, uint32_t ctr) {
  uint32_t h = chain * 0x9E3779B9u ^ (ctr * 0x85EBCA6Bu);
  h ^= h >> 16; h *= 0x7FEB352Du;
  h ^= h >> 15; h *= 0x846CA68Bu;
  h ^= h >> 16;
  return h;
}
__device__ __forceinline__ float urand(uint32_t chain, uint32_t ctr) {
  return (float)(hash32(chain, ctr) >> 8) * (1.0f / 16777216.0f);
}
__device__ __forceinline__ uint32_t f2bf(float f) {
  uint32_t b = __builtin_bit_cast(uint32_t, f);
  return (b + 0x7FFFu + ((b >> 16) & 1u)) >> 16;
}
__device__ __forceinline__ float bf2f(uint16_t u) {
  uint32_t b = ((uint32_t)u) << 16;
  return __builtin_bit_cast(float, b);
}
__device__ __forceinline__ int cperm(int c) {
  return ((c >> 2) & 3) * 32 + (c >> 4) * 4 + (c & 3);
}
__device__ __forceinline__ int swz(int p) {
  int win = p >> 5, o = p & 31;
  return win * 32 + (((o >> 3) + win) & 3) * 8 + (o & 7);
}

// ------------- Kernel A: lpib[ks] = bf16 partial of x @ alpha^T (split-K x4, MFMA) -------------
__global__ __launch_bounds__(256) void k_lingemm(const float* __restrict__ x,
                                                 const float* __restrict__ alpha,
                                                 uint16_t* __restrict__ lpib) {
  __shared__ uint4 sA[256];
  __shared__ uint4 sB[1024];
  const int t = threadIdx.x;
  const int mt = blockIdx.x >> 2;
  const int ks = blockIdx.x & 3;
  const int m0 = mt * 32;
  const int w = t >> 6;
  const int l = t & 63;

  f32x4 acc[2][2] = {{{0.f, 0.f, 0.f, 0.f}, {0.f, 0.f, 0.f, 0.f}},
                     {{0.f, 0.f, 0.f, 0.f}, {0.f, 0.f, 0.f, 0.f}}};

  for (int kk = 0; kk < 4; ++kk) {
    const int k0 = ks * 256 + kk * 64;
    __syncthreads();
    {
      int row = t >> 3, c = t & 7;
      const float* px = &x[(m0 + row) * Ff + k0 + c * 8];
      float4 f0 = *(const float4*)px;
      float4 f1 = *(const float4*)(px + 4);
      uint4 v;
      v.x = f2bf(f0.x) | (f2bf(f0.y) << 16);
      v.y = f2bf(f0.z) | (f2bf(f0.w) << 16);
      v.z = f2bf(f1.x) | (f2bf(f1.y) << 16);
      v.w = f2bf(f1.z) | (f2bf(f1.w) << 16);
      sA[row * 8 + (c ^ (row & 7))] = v;
      #pragma unroll
      for (int rr = 0; rr < 4; ++rr) {
        int idx = t + rr * 256;
        int rowb = idx >> 3, cb = idx & 7;
        const float* pa = &alpha[rowb * Ff + k0 + cb * 8];
        float4 g0 = *(const float4*)pa;
        float4 g1 = *(const float4*)(pa + 4);
        uint4 vb;
        vb.x = f2bf(g0.x) | (f2bf(g0.y) << 16);
        vb.y = f2bf(g0.z) | (f2bf(g0.w) << 16);
        vb.z = f2bf(g1.x) | (f2bf(g1.y) << 16);
        vb.w = f2bf(g1.z) | (f2bf(g1.w) << 16);
        sB[rowb * 8 + (cb ^ (rowb & 7))] = vb;
      }
    }
    __syncthreads();
    #pragma unroll
    for (int kc = 0; kc < 2; ++kc) {
      int chunk = kc * 4 + (l >> 4);
      bf8 av[2], bv[2];
      #pragma unroll
      for (int fm = 0; fm < 2; ++fm) {
        int row = fm * 16 + (l & 15);
        av[fm] = __builtin_bit_cast(bf8, sA[row * 8 + (chunk ^ (row & 7))]);
      }
      #pragma unroll
      for (int fn = 0; fn < 2; ++fn) {
        int rowb = w * 32 + fn * 16 + (l & 15);
        bv[fn] = __builtin_bit_cast(bf8, sB[rowb * 8 + (chunk ^ (rowb & 7))]);
      }
      #pragma unroll
      for (int fm = 0; fm < 2; ++fm)
        #pragma unroll
        for (int fn = 0; fn < 2; ++fn)
          acc[fm][fn] = __builtin_amdgcn_mfma_f32_16x16x32_bf16(av[fm], bv[fn], acc[fm][fn], 0, 0, 0);
    }
  }
  #pragma unroll
  for (int fm = 0; fm < 2; ++fm)
    #pragma unroll
    for (int fn = 0; fn < 2; ++fn)
      #pragma unroll
      for (int r = 0; r < 4; ++r) {
        int row = m0 + fm * 16 + (l >> 4) * 4 + r;
        int col = w * 32 + fn * 16 + (l & 15);
        lpib[ks * NM + row * Mm + col] = (uint16_t)f2bf(acc[fm][fn][r]);
      }
}

// prefetch table slice for step j into named regs (B3 is uint2)
#define PF(B0, B1, B2, B3, bit, j) {                                          \
    const __half* p_ = tab + ((bit) ? TOFF : 0) + (j) * SCP + hq * 32;        \
    B0 = *(const uint4*)(p_ + rot0);                                          \
    B1 = *(const uint4*)(p_ + rot1);                                          \
    B2 = *(const uint4*)(p_ + rot2);                                          \
    B3 = *(const uint2*)(p_ + rot3); }

// one branch-free Gibbs step on named regs (E2_0..E2_13 uint32, Sb updated in place)
#define STEP(B0, B1, B2, B3, zjp, eyel, u, bout) {                            \
    float d0_ = d2a(E2_0, B0.x, 0.0f), d1_ = d2a(E2_1, B0.y, 0.0f);           \
    float d2_ = d2a(E2_2, B0.z, 0.0f), d3_ = d2a(E2_3, B0.w, 0.0f);           \
    d0_ = d2a(E2_4, B1.x, d0_); d1_ = d2a(E2_5, B1.y, d1_);                   \
    d2_ = d2a(E2_6, B1.z, d2_); d3_ = d2a(E2_7, B1.w, d3_);                   \
    d0_ = d2a(E2_8, B2.x, d0_); d1_ = d2a(E2_9, B2.y, d1_);                   \
    d2_ = d2a(E2_10, B2.z, d2_); d3_ = d2a(E2_11, B2.w, d3_);                 \
    d0_ = d2a(E2_12, B3.x, d0_); d1_ = d2a(E2_13, B3.y, d1_);                 \
    float D_ = qsum4((d0_ + d1_) + (d2_ + d3_));                              \
    float Sp_ = (zjp) ? Sb : D_;                                              \
    float Sn_ = (zjp) ? D_ : Sb;                                              \
    float odds_ = (eyel) * Sn_ * __builtin_amdgcn_rcpf(Sp_);                  \
    uint32_t znp_ = ((u) * (1.0f + odds_) < odds_) ? 1u : 0u;                 \
    bool fl_ = ((znp_ ^ (zjp)) != 0u);                                        \
    E2_0 = fl_ ? pkmul(E2_0, B0.x) : E2_0;                                    \
    E2_1 = fl_ ? pkmul(E2_1, B0.y) : E2_1;                                    \
    E2_2 = fl_ ? pkmul(E2_2, B0.z) : E2_2;                                    \
    E2_3 = fl_ ? pkmul(E2_3, B0.w) : E2_3;                                    \
    E2_4 = fl_ ? pkmul(E2_4, B1.x) : E2_4;                                    \
    E2_5 = fl_ ? pkmul(E2_5, B1.y) : E2_5;                                    \
    E2_6 = fl_ ? pkmul(E2_6, B1.z) : E2_6;                                    \
    E2_7 = fl_ ? pkmul(E2_7, B1.w) : E2_7;                                    \
    E2_8 = fl_ ? pkmul(E2_8, B2.x) : E2_8;                                    \
    E2_9 = fl_ ? pkmul(E2_9, B2.y) : E2_9;                                    \
    E2_10 = fl_ ? pkmul(E2_10, B2.z) : E2_10;                                 \
    E2_11 = fl_ ? pkmul(E2_11, B2.w) : E2_11;                                 \
    E2_12 = fl_ ? pkmul(E2_12, B3.x) : E2_12;                                 \
    E2_13 = fl_ ? pkmul(E2_13, B3.y) : E2_13;                                 \
    Sb = fl_ ? D_ : Sb;                                                       \
    bout = znp_; }

#define MKE(k)                                                                \
  {                                                                           \
    float2 b0v = *(const float2*)&b0p[c0m + 2 * (k)];                         \
    float ea_ = __expf(acc[(2 * (k)) >> 2][(2 * (k)) & 3] + b0v.x) * ESC;     \
    float eb_ = __expf(acc[(2 * (k) + 1) >> 2][(2 * (k) + 1) & 3] + b0v.y) * ESC; \
    __half2 hh_ = __floats2half2_rn(ea_, eb_);                                \
    E2_##k = __builtin_bit_cast(uint32_t, hh_);                               \
  }

#define SHF(k) E2_##k = (uint32_t)__shfl((int)E2_##k, src, 64);

// ------------- Kernel B: fused init(MFMA) + branch-free asm Gibbs sweep + final reduction -------------
// 256 blocks x 1024 threads: 8 n-rows, 256 chains/block, 4 lanes/chain (lane-quads).
__global__ __launch_bounds__(1024, 4) void k_gibbs(const float* __restrict__ beta0g,
                                                   const float* __restrict__ betag,
                                                   const int* __restrict__ yg,
                                                   const float* __restrict__ alpha0,
                                                   const uint16_t* __restrict__ lpib,
                                                   float* __restrict__ out) {
  __shared__ __attribute__((aligned(16))) char SM[83808];
  uint16_t* bsb = (uint16_t*)SM;            // phase A: beta bf16 [112][128] swizzled (28672 B)
  __half* tab = (__half*)SM;                // phase B: ep2 @0, em2 @TOFF (65664 B)
  float* elpi = (float*)(SM + 65600);       // [8][ELS]; aliased by red in final phase
  float* lpil = (float*)(SM + 69824);       // [8][128]
  uint32_t* zsl = (uint32_t*)(SM + 73920);  // [256][4]
  float* lsel = (float*)(SM + 78016);       // [256]
  int* yl = (int*)(SM + 79040);             // [8]
  float* b0p = (float*)(SM + 79072);        // [128] permuted beta0
  float* eyelLUT = (float*)(SM + 79584);    // [8][ELS]: exp(2*beta[y][j]) * exp(lpi[n][j])
  float* red = (float*)(SM + 65600);        // [1024] final-phase alias

  const int t = threadIdx.x;
  const int n0 = blockIdx.x * 8;
  const int L = t & 63;

  // ---- phase A: stage beta bf16 (row-swizzled 16B chunks), permuted beta0, lpi sums ----
  for (int idx = t; idx < 112 * 32; idx += 1024) {
    int row = idx >> 5, u = idx & 31;
    int rr = (row < Cc) ? row : 0;
    float4 v = *(const float4*)&betag[rr * Mm + u * 4];
    uint2 o;
    o.x = f2bf(v.x) | (f2bf(v.y) << 16);
    o.y = f2bf(v.z) | (f2bf(v.w) << 16);
    int k = u >> 1, sub = u & 1;
    int kp = k ^ (row & 15);
    *(uint2*)&bsb[row * 128 + kp * 8 + sub * 4] = o;
  }
  if (t < 128) b0p[cperm(t)] = (t < Cc) ? beta0g[t] : 0.0f;
  {
    int nls = t >> 7, j = t & 127;
    int g = (n0 + nls) * Mm + j;
    float lv = bf2f(lpib[g]) + bf2f(lpib[NM + g]) + bf2f(lpib[2 * NM + g]) +
               bf2f(lpib[3 * NM + g]) + alpha0[j];
    lpil[nls * Mm + j] = lv;
    elpi[nls * ELS + j] = __expf(lv);
  }
  if (t < 8) yl[t] = yg[n0 + t];
  __syncthreads();

  // eyelLUT: coalesced global beta read (L2-hot), f32 exact
  {
    int nl2 = t >> 7, j = t & 127;
    float b = betag[yl[nl2] * Mm + j];
    eyelLUT[nl2 * ELS + j] = __expf(2.0f * b) * elpi[nl2 * ELS + j];
  }

  // quad mapping: chain cl = t>>2, slice hq = t&3
  const int cl = t >> 2;
  const int hq = t & 3;
  const int nl = cl >> 5;                 // wave-uniform
  const int s = cl & 31;
  const uint32_t chain = (uint32_t)((n0 + nl) * Ss + s);

  // ---- Z0: lane draws word hq of chain cl ----
  uint32_t zz = 0;
  {
    #pragma unroll 1
    for (int b5 = 0; b5 < 32; ++b5) {
      int mloc = (b5 + hq * 8) & 31;
      int m = hq * 32 + mloc;
      float u = urand(chain, (uint32_t)m);
      float el = elpi[nl * ELS + m];
      zz |= (u * (1.0f + el) < el) ? (1u << mloc) : 0u;
    }
  }

  // ---- init lin = Z0 . beta via MFMA (MFMA roles: chain = L&15, window hw = L>>4) ----
  f32x4 acc[7];
  #pragma unroll
  for (int T = 0; T < 7; ++T) acc[T] = (f32x4){0.f, 0.f, 0.f, 0.f};
  {
    const int liw = L & 15, hw = L >> 4;
    #pragma unroll
    for (int ks = 0; ks < 4; ++ks) {
      uint32_t zw = (uint32_t)__shfl((int)zz, (liw << 2) | ks, 64);
      uint32_t bits8 = (zw >> (hw * 8)) & 0xFFu;
      uint4 pk;
      {
        uint32_t p0 = ((bits8 >> 0) & 1u) ? 0x3F80u : 0xBF80u;
        uint32_t p1 = ((bits8 >> 1) & 1u) ? 0x3F80u : 0xBF80u;
        uint32_t p2 = ((bits8 >> 2) & 1u) ? 0x3F80u : 0xBF80u;
        uint32_t p3 = ((bits8 >> 3) & 1u) ? 0x3F80u : 0xBF80u;
        uint32_t p4 = ((bits8 >> 4) & 1u) ? 0x3F80u : 0xBF80u;
        uint32_t p5 = ((bits8 >> 5) & 1u) ? 0x3F80u : 0xBF80u;
        uint32_t p6 = ((bits8 >> 6) & 1u) ? 0x3F80u : 0xBF80u;
        uint32_t p7 = ((bits8 >> 7) & 1u) ? 0x3F80u : 0xBF80u;
        pk.x = p0 | (p1 << 16); pk.y = p2 | (p3 << 16);
        pk.z = p4 | (p5 << 16); pk.w = p6 | (p7 << 16);
      }
      bf8 B = __builtin_bit_cast(bf8, pk);
      #pragma unroll
      for (int T = 0; T < 7; ++T) {
        int row = T * 16 + liw;
        int kk = ks * 4 + hw;
        bf8 A = __builtin_bit_cast(bf8, *(const uint4*)&bsb[row * 128 + (kk ^ (row & 15)) * 8]);
        acc[T] = __builtin_amdgcn_mfma_f32_16x16x32_bf16(A, B, acc[T], 0, 0, 0);
      }
    }
  }

  // ---- E = exp(lin + beta0)*2^-6 packed f16 (MFMA layout), then quad shuffle ----
  uint32_t E2_0, E2_1, E2_2, E2_3, E2_4, E2_5, E2_6, E2_7;
  uint32_t E2_8, E2_9, E2_10, E2_11, E2_12, E2_13;
  {
    int c0m = (L >> 4) * 32;
    MKE(0) MKE(1) MKE(2) MKE(3) MKE(4) MKE(5) MKE(6)
    MKE(7) MKE(8) MKE(9) MKE(10) MKE(11) MKE(12) MKE(13)
    if ((L >> 4) != 0) { E2_12 = 0u; E2_13 = 0u; }  // classes >= 100
  }
  {
    int src = (L >> 2) | ((L & 3) << 4);
    SHF(0) SHF(1) SHF(2) SHF(3) SHF(4) SHF(5) SHF(6)
    SHF(7) SHF(8) SHF(9) SHF(10) SHF(11) SHF(12) SHF(13)
  }
  uint32_t zw0 = (uint32_t)__shfl((int)zz, (L & ~3) | 0, 64);
  uint32_t zw1 = (uint32_t)__shfl((int)zz, (L & ~3) | 1, 64);
  uint32_t zw2 = (uint32_t)__shfl((int)zz, (L & ~3) | 2, 64);
  uint32_t zw3 = (uint32_t)__shfl((int)zz, (L & ~3) | 3, 64);

  const uint32_t ONE2 = 0x3C003C00u;   // (1.0h, 1.0h)
  float Sb;
  {
    float d0_ = d2a(E2_0, ONE2, 0.0f), d1_ = d2a(E2_1, ONE2, 0.0f);
    float d2_ = d2a(E2_2, ONE2, 0.0f), d3_ = d2a(E2_3, ONE2, 0.0f);
    d0_ = d2a(E2_4, ONE2, d0_); d1_ = d2a(E2_5, ONE2, d1_);
    d2_ = d2a(E2_6, ONE2, d2_); d3_ = d2a(E2_7, ONE2, d3_);
    d0_ = d2a(E2_8, ONE2, d0_); d1_ = d2a(E2_9, ONE2, d1_);
    d2_ = d2a(E2_10, ONE2, d2_); d3_ = d2a(E2_11, ONE2, d3_);
    d0_ = d2a(E2_12, ONE2, d0_); d1_ = d2a(E2_13, ONE2, d1_);
    Sb = qsum4((d0_ + d1_) + (d2_ + d3_));
  }

  // ---- phase B: rebuild LDS as f16 tables, permuted+chunk-rotated positions ----
  __syncthreads();
  for (int idx = t; idx < 32 * Cc; idx += 1024) {
    int j4 = idx / Cc;
    int c = idx - j4 * Cc;
    int ps = swz(cperm(c));
    float4 bv = *(const float4*)&betag[c * Mm + j4 * 4];
    int j = j4 * 4;
    tab[(j + 0) * SCP + ps] = __float2half(__expf(2.0f * bv.x));
    tab[TOFF + (j + 0) * SCP + ps] = __float2half(__expf(-2.0f * bv.x));
    tab[(j + 1) * SCP + ps] = __float2half(__expf(2.0f * bv.y));
    tab[TOFF + (j + 1) * SCP + ps] = __float2half(__expf(-2.0f * bv.y));
    tab[(j + 2) * SCP + ps] = __float2half(__expf(2.0f * bv.z));
    tab[TOFF + (j + 2) * SCP + ps] = __float2half(__expf(-2.0f * bv.z));
    tab[(j + 3) * SCP + ps] = __float2half(__expf(2.0f * bv.w));
    tab[TOFF + (j + 3) * SCP + ps] = __float2half(__expf(-2.0f * bv.w));
  }
  for (int idx = t; idx < Mm * 28; idx += 1024) {
    int j = idx / 28;
    int c = Cc + (idx - j * 28);
    int ps = swz(cperm(c));
    tab[j * SCP + ps] = __float2half(1.0f);
    tab[TOFF + j * SCP + ps] = __float2half(1.0f);
  }
  for (int idx = t; idx < Mm * 16; idx += 1024) {
    int j = idx >> 4;
    int win = (idx >> 2) & 3, o = 28 + (idx & 3);
    int ps = win * 32 + (((o >> 3) + win) & 3) * 8 + (o & 7);
    tab[j * SCP + ps] = __float2half(1.0f);
    tab[TOFF + j * SCP + ps] = __float2half(1.0f);
  }
  __syncthreads();

  // ---- Gibbs sweep: pair-level ping-pong, depth-2/3 static prefetch, branch-free ----
  const int rot0 = ((0 + hq) & 3) * 8;
  const int rot1 = ((1 + hq) & 3) * 8;
  const int rot2 = ((2 + hq) & 3) * 8;
  const int rot3 = ((3 + hq) & 3) * 8;

  uint4 sA00, sA01, sA02, sA10, sA11, sA12;
  uint2 sA03, sA13;
  uint4 sB00, sB01, sB02, sB10, sB11, sB12;
  uint2 sB03, sB13;

  PF(sA00, sA01, sA02, sA03, zw0 & 1u, 0)
  PF(sA10, sA11, sA12, sA13, (zw0 >> 1) & 1u, 1)
  float4 eycur = *(const float4*)&eyelLUT[nl * ELS];

  #pragma unroll
  for (int w = 0; w < 4; ++w) {
    uint32_t zwv = (w == 0) ? zw0 : ((w == 1) ? zw1 : ((w == 2) ? zw2 : zw3));
    const uint32_t nextw = (w == 0) ? zw1 : ((w == 1) ? zw2 : ((w == 2) ? zw3 : 0u));
    #pragma unroll 1
    for (int g = 0; g < 8; ++g) {
      const int jb = w * 32 + g * 4;
      const int sh = g * 4;
      uint64_t win = (zwv >> sh) | ((uint64_t)nextw << (32 - sh));
      uint32_t b0 = (uint32_t)win & 1u;
      uint32_t b1 = ((uint32_t)(win >> 1)) & 1u;
      uint32_t b2 = ((uint32_t)(win >> 2)) & 1u;
      uint32_t b3 = ((uint32_t)(win >> 3)) & 1u;
      uint32_t c4 = ((uint32_t)(win >> 4)) & 1u;
      uint32_t c5 = ((uint32_t)(win >> 5)) & 1u;
      uint32_t h1 = hash32(chain, 256u + (uint32_t)jb);
      uint32_t h2 = hash32(chain, 258u + (uint32_t)jb);
      float u0 = (float)(h1 & 0xFFFFu) * (1.0f / 65536.0f);
      float u1 = (float)(h1 >> 16) * (1.0f / 65536.0f);
      float u2 = (float)(h2 & 0xFFFFu) * (1.0f / 65536.0f);
      float u3 = (float)(h2 >> 16) * (1.0f / 65536.0f);

      PF(sB00, sB01, sB02, sB03, b2, jb + 2)
      PF(sB10, sB11, sB12, sB13, b3, jb + 3)
      __builtin_amdgcn_sched_barrier(0);
      STEP(sA00, sA01, sA02, sA03, b0, eycur.x, u0, b0)
      STEP(sA10, sA11, sA12, sA13, b1, eycur.y, u1, b1)
      PF(sA00, sA01, sA02, sA03, c4, (jb + 4) & 127)
      PF(sA10, sA11, sA12, sA13, c5, (jb + 5) & 127)
      float4 eyn = *(const float4*)&eyelLUT[nl * ELS + ((jb + 4) & 127)];
      __builtin_amdgcn_sched_barrier(0);
      STEP(sB00, sB01, sB02, sB03, b2, eycur.z, u2, b2)
      STEP(sB10, sB11, sB12, sB13, b3, eycur.w, u3, b3)
      eycur = eyn;

      uint32_t nib = b0 | (b1 << 1) | (b2 << 2) | (b3 << 3);
      zwv = (zwv & ~(0xFu << sh)) | (nib << sh);
    }
    if (w == 0) zw0 = zwv; else if (w == 1) zw1 = zwv;
    else if (w == 2) zw2 = zwv; else zw3 = zwv;
  }

  // ---- outputs to LDS ----
  float Sf;
  {
    float d0_ = d2a(E2_0, ONE2, 0.0f), d1_ = d2a(E2_1, ONE2, 0.0f);
    float d2_ = d2a(E2_2, ONE2, 0.0f), d3_ = d2a(E2_3, ONE2, 0.0f);
    d0_ = d2a(E2_4, ONE2, d0_); d1_ = d2a(E2_5, ONE2, d1_);
    d2_ = d2a(E2_6, ONE2, d2_); d3_ = d2a(E2_7, ONE2, d3_);
    d0_ = d2a(E2_8, ONE2, d0_); d1_ = d2a(E2_9, ONE2, d1_);
    d2_ = d2a(E2_10, ONE2, d2_); d3_ = d2a(E2_11, ONE2, d3_);
    d0_ = d2a(E2_12, ONE2, d0_); d1_ = d2a(E2_13, ONE2, d1_);
    Sf = qsum4((d0_ + d1_) + (d2_ + d3_));
  }
  if (hq == 0) {
    lsel[cl] = __logf(Sf) + ESCLOG;
    zsl[cl * 4 + 0] = zw0; zsl[cl * 4 + 1] = zw1;
    zsl[cl * 4 + 2] = zw2; zsl[cl * 4 + 3] = zw3;
  }
  __syncthreads();

  // ---- fused final: moments + all four terms for this block's 8 n-rows ----
  {
    int nl2 = t >> 7;
    int mp = t & 127;
    int wsel = mp >> 5, sh0 = mp & 31;
    int cnt = 0;
    #pragma unroll 1
    for (int s2 = 0; s2 < 32; ++s2)
      cnt += (int)((zsl[(nl2 * 32 + s2) * 4 + wsel] >> sh0) & 1u);
    float EI = (float)cnt * (1.0f / 32.0f);
    float EII = 2.0f * EI - 1.0f;
    float l = lpil[nl2 * Mm + mp];
    int yv2 = yl[nl2];
    float bb = betag[yv2 * Mm + mp];
    float sp = (l > 20.0f) ? l : __logf(1.0f + __expf(l));
    float term = EII * bb + EI * l - sp;
    if (t < 256) term -= lsel[t] * (1.0f / 32.0f);
    if (t < 8) term += beta0g[yl[t]];
    red[t] = term;
  }
  __syncthreads();
  for (int off = 512; off > 0; off >>= 1) {
    if (t < off) red[t] += red[t + off];
    __syncthreads();
  }
  if (t == 0) atomicAdd(out, red[0]);
}

extern "C" void kernel_launch(void* const* d_in, const int* in_sizes, int n_in,
                              void* d_out, int out_size, void* d_ws, size_t ws_size,
                              hipStream_t stream) {
  const float* x = (const float*)d_in[0];
  const int* y = (const int*)d_in[1];
  const float* alpha0 = (const float*)d_in[2];
  const float* alpha = (const float*)d_in[3];
  const float* beta0 = (const float*)d_in[4];
  const float* beta = (const float*)d_in[5];
  float* out = (float*)d_out;

  uint16_t* lpib = (uint16_t*)d_ws;   // 4 bf16 split-K planes = 2 MB

  hipMemsetAsync(d_out, 0, sizeof(float), stream);
  k_lingemm<<<256, 256, 0, stream>>>(x, alpha, lpib);
  k_gibbs<<<256, 1024, 0, stream>>>(beta0, beta, y, alpha0, lpib, out);
}

// Round 13
// 90.960 us; speedup vs baseline: 1.1022x; 1.1022x over previous
//
#include <hip/hip_runtime.h>
#include <hip/hip_fp16.h>
#include <stdint.h>

#define Nn 2048
#define Ff 1024
#define Mm 128
#define Cc 100
#define Ss 32
#define NM (Nn * Mm)
#define ELS 132
#define SCP 128          // table row stride in halfs
#define TOFF 16416       // em2 offset in halfs (byte 32832 == 64 mod 128 -> +4 bank-quad phase)
#define ESC 0.015625f          // 2^-6 scale on E
#define ESCLOG 4.15888308336f  // 6*ln2

typedef _Float16 h2f __attribute__((ext_vector_type(2)));
typedef short bf8 __attribute__((ext_vector_type(8)));
typedef float f32x4 __attribute__((ext_vector_type(4)));

__device__ __forceinline__ float qsum4(float x) {
  int a = __builtin_amdgcn_update_dpp(0, __builtin_bit_cast(int, x), 0xB1, 0xF, 0xF, false);
  float xf = x + __builtin_bit_cast(float, a);
  int b = __builtin_amdgcn_update_dpp(0, __builtin_bit_cast(int, xf), 0x4E, 0xF, 0xF, false);
  return xf + __builtin_bit_cast(float, b);
}

__device__ __forceinline__ float dot2f(h2f a, h2f b, float c) {
#if __has_builtin(__builtin_amdgcn_fdot2)
  return __builtin_amdgcn_fdot2(a, b, c, false);
#else
  return fmaf((float)a[0], (float)b[0], fmaf((float)a[1], (float)b[1], c));
#endif
}
__device__ __forceinline__ float d2(__half2 e, uint32_t v, float c) {
  return dot2f(__builtin_bit_cast(h2f, e), __builtin_bit_cast(h2f, v), c);
}
__device__ __forceinline__ __half2 m2(__half2 e, uint32_t v) {
  return __hmul2(e, __builtin_bit_cast(__half2, v));
}

__device__ __forceinline__ uint32_t hash32(uint32_t chain, uint32_t ctr) {
  uint32_t h = chain * 0x9E3779B9u ^ (ctr * 0x85EBCA6Bu);
  h ^= h >> 16; h *= 0x7FEB352Du;
  h ^= h >> 15; h *= 0x846CA68Bu;
  h ^= h >> 16;
  return h;
}
__device__ __forceinline__ float urand(uint32_t chain, uint32_t ctr) {
  return (float)(hash32(chain, ctr) >> 8) * (1.0f / 16777216.0f);
}
__device__ __forceinline__ uint32_t f2bf(float f) {
  uint32_t b = __builtin_bit_cast(uint32_t, f);
  return (b + 0x7FFFu + ((b >> 16) & 1u)) >> 16;
}
__device__ __forceinline__ float bf2f(uint16_t u) {
  uint32_t b = ((uint32_t)u) << 16;
  return __builtin_bit_cast(float, b);
}
__device__ __forceinline__ int cperm(int c) {
  return ((c >> 2) & 3) * 32 + (c >> 4) * 4 + (c & 3);
}
__device__ __forceinline__ int swz(int p) {
  int win = p >> 5, o = p & 31;
  return win * 32 + (((o >> 3) + win) & 3) * 8 + (o & 7);
}

// ------------- Kernel A: lpib[ks] = bf16 partial of x @ alpha^T (split-K x4, MFMA) -------------
__global__ __launch_bounds__(256) void k_lingemm(const float* __restrict__ x,
                                                 const float* __restrict__ alpha,
                                                 uint16_t* __restrict__ lpib) {
  __shared__ uint4 sA[256];
  __shared__ uint4 sB[1024];
  const int t = threadIdx.x;
  const int mt = blockIdx.x >> 2;
  const int ks = blockIdx.x & 3;
  const int m0 = mt * 32;
  const int w = t >> 6;
  const int l = t & 63;

  f32x4 acc[2][2] = {{{0.f, 0.f, 0.f, 0.f}, {0.f, 0.f, 0.f, 0.f}},
                     {{0.f, 0.f, 0.f, 0.f}, {0.f, 0.f, 0.f, 0.f}}};

  for (int kk = 0; kk < 4; ++kk) {
    const int k0 = ks * 256 + kk * 64;
    __syncthreads();
    {
      int row = t >> 3, c = t & 7;
      const float* px = &x[(m0 + row) * Ff + k0 + c * 8];
      float4 f0 = *(const float4*)px;
      float4 f1 = *(const float4*)(px + 4);
      uint4 v;
      v.x = f2bf(f0.x) | (f2bf(f0.y) << 16);
      v.y = f2bf(f0.z) | (f2bf(f0.w) << 16);
      v.z = f2bf(f1.x) | (f2bf(f1.y) << 16);
      v.w = f2bf(f1.z) | (f2bf(f1.w) << 16);
      sA[row * 8 + (c ^ (row & 7))] = v;
      #pragma unroll
      for (int rr = 0; rr < 4; ++rr) {
        int idx = t + rr * 256;
        int rowb = idx >> 3, cb = idx & 7;
        const float* pa = &alpha[rowb * Ff + k0 + cb * 8];
        float4 g0 = *(const float4*)pa;
        float4 g1 = *(const float4*)(pa + 4);
        uint4 vb;
        vb.x = f2bf(g0.x) | (f2bf(g0.y) << 16);
        vb.y = f2bf(g0.z) | (f2bf(g0.w) << 16);
        vb.z = f2bf(g1.x) | (f2bf(g1.y) << 16);
        vb.w = f2bf(g1.z) | (f2bf(g1.w) << 16);
        sB[rowb * 8 + (cb ^ (rowb & 7))] = vb;
      }
    }
    __syncthreads();
    #pragma unroll
    for (int kc = 0; kc < 2; ++kc) {
      int chunk = kc * 4 + (l >> 4);
      bf8 av[2], bv[2];
      #pragma unroll
      for (int fm = 0; fm < 2; ++fm) {
        int row = fm * 16 + (l & 15);
        av[fm] = __builtin_bit_cast(bf8, sA[row * 8 + (chunk ^ (row & 7))]);
      }
      #pragma unroll
      for (int fn = 0; fn < 2; ++fn) {
        int rowb = w * 32 + fn * 16 + (l & 15);
        bv[fn] = __builtin_bit_cast(bf8, sB[rowb * 8 + (chunk ^ (rowb & 7))]);
      }
      #pragma unroll
      for (int fm = 0; fm < 2; ++fm)
        #pragma unroll
        for (int fn = 0; fn < 2; ++fn)
          acc[fm][fn] = __builtin_amdgcn_mfma_f32_16x16x32_bf16(av[fm], bv[fn], acc[fm][fn], 0, 0, 0);
    }
  }
  #pragma unroll
  for (int fm = 0; fm < 2; ++fm)
    #pragma unroll
    for (int fn = 0; fn < 2; ++fn)
      #pragma unroll
      for (int r = 0; r < 4; ++r) {
        int row = m0 + fm * 16 + (l >> 4) * 4 + r;
        int col = w * 32 + fn * 16 + (l & 15);
        lpib[ks * NM + row * Mm + col] = (uint16_t)f2bf(acc[fm][fn][r]);
      }
}

// prefetch table slice for step j into named regs (B3 is uint2)
#define PF(B0, B1, B2, B3, bit, j) {                                          \
    const __half* p_ = tab + ((bit) ? TOFF : 0) + (j) * SCP + hq * 32;        \
    B0 = *(const uint4*)(p_ + rot0);                                          \
    B1 = *(const uint4*)(p_ + rot1);                                          \
    B2 = *(const uint4*)(p_ + rot2);                                          \
    B3 = *(const uint2*)(p_ + rot3); }

// one Gibbs step on named regs; rcp-free accept test: u*Spos < (1-u)*eyel*Sneg
#define STEP(B0, B1, B2, B3, zjp, eyel, u, um1, bout) {                       \
    float d0_ = d2(E2_0, B0.x, 0.f), d1_ = d2(E2_1, B0.y, 0.f);               \
    float d2_ = d2(E2_2, B0.z, 0.f), d3_ = d2(E2_3, B0.w, 0.f);               \
    d0_ = d2(E2_4, B1.x, d0_); d1_ = d2(E2_5, B1.y, d1_);                     \
    d2_ = d2(E2_6, B1.z, d2_); d3_ = d2(E2_7, B1.w, d3_);                     \
    d0_ = d2(E2_8, B2.x, d0_); d1_ = d2(E2_9, B2.y, d1_);                     \
    d2_ = d2(E2_10, B2.z, d2_); d3_ = d2(E2_11, B2.w, d3_);                   \
    d0_ = d2(E2_12, B3.x, d0_); d1_ = d2(E2_13, B3.y, d1_);                   \
    float D_ = qsum4((d0_ + d1_) + (d2_ + d3_));                              \
    float Sp_ = (zjp) ? Sb : D_;                                              \
    float Sn_ = (zjp) ? D_ : Sb;                                              \
    float tn_ = (eyel) * Sn_;                                                 \
    uint32_t znp_ = ((u) * Sp_ < (um1) * tn_) ? 1u : 0u;                      \
    if ((znp_ ^ (zjp)) != 0u) {                                               \
      E2_0 = m2(E2_0, B0.x); E2_1 = m2(E2_1, B0.y);                           \
      E2_2 = m2(E2_2, B0.z); E2_3 = m2(E2_3, B0.w);                           \
      E2_4 = m2(E2_4, B1.x); E2_5 = m2(E2_5, B1.y);                           \
      E2_6 = m2(E2_6, B1.z); E2_7 = m2(E2_7, B1.w);                           \
      E2_8 = m2(E2_8, B2.x); E2_9 = m2(E2_9, B2.y);                           \
      E2_10 = m2(E2_10, B2.z); E2_11 = m2(E2_11, B2.w);                       \
      E2_12 = m2(E2_12, B3.x); E2_13 = m2(E2_13, B3.y);                       \
      Sb = D_;                                                                \
    }                                                                         \
    bout = znp_; }

#define MKE(k)                                                                \
  {                                                                           \
    float2 b0v = *(const float2*)&b0p[c0m + 2 * (k)];                         \
    float ea_ = __expf(acc[(2 * (k)) >> 2][(2 * (k)) & 3] + b0v.x) * ESC;     \
    float eb_ = __expf(acc[(2 * (k) + 1) >> 2][(2 * (k) + 1) & 3] + b0v.y) * ESC; \
    E2_##k = __floats2half2_rn(ea_, eb_);                                     \
  }

#define SHF(k) E2_##k = __builtin_bit_cast(__half2,                           \
    (uint32_t)__shfl((int)__builtin_bit_cast(uint32_t, E2_##k), src, 64));

// ------------- Kernel B: fused init(MFMA) + deep-prefetch Gibbs sweep + final reduction -------------
// 256 blocks x 1024 threads: 8 n-rows, 256 chains/block, 4 lanes/chain (lane-quads).
__global__ __launch_bounds__(1024, 4) void k_gibbs(const float* __restrict__ beta0g,
                                                   const float* __restrict__ betag,
                                                   const int* __restrict__ yg,
                                                   const float* __restrict__ alpha0,
                                                   const uint16_t* __restrict__ lpib,
                                                   float* __restrict__ out) {
  __shared__ __attribute__((aligned(16))) char SM[83808];
  uint16_t* bsb = (uint16_t*)SM;            // phase A: beta bf16 [112][128] swizzled (28672 B)
  __half* tab = (__half*)SM;                // phase B: ep2 @0, em2 @TOFF (65664 B)
  float* elpi = (float*)(SM + 65600);       // [8][ELS]; aliased by red in final phase
  float* lpil = (float*)(SM + 69824);       // [8][128]
  uint32_t* zsl = (uint32_t*)(SM + 73920);  // [256][4]
  float* lsel = (float*)(SM + 78016);       // [256]
  int* yl = (int*)(SM + 79040);             // [8]
  float* b0p = (float*)(SM + 79072);        // [128] permuted beta0
  float* eyelLUT = (float*)(SM + 79584);    // [8][ELS]: exp(2*beta[y][j]) * exp(lpi[n][j])
  float* red = (float*)(SM + 65600);        // [1024] final-phase alias

  const int t = threadIdx.x;
  const int n0 = blockIdx.x * 8;
  const int L = t & 63;

  // ---- phase A: stage beta bf16 (row-swizzled 16B chunks), permuted beta0, lpi sums ----
  for (int idx = t; idx < 112 * 32; idx += 1024) {
    int row = idx >> 5, u = idx & 31;
    int rr = (row < Cc) ? row : 0;
    float4 v = *(const float4*)&betag[rr * Mm + u * 4];
    uint2 o;
    o.x = f2bf(v.x) | (f2bf(v.y) << 16);
    o.y = f2bf(v.z) | (f2bf(v.w) << 16);
    int k = u >> 1, sub = u & 1;
    int kp = k ^ (row & 15);
    *(uint2*)&bsb[row * 128 + kp * 8 + sub * 4] = o;
  }
  if (t < 128) b0p[cperm(t)] = (t < Cc) ? beta0g[t] : 0.0f;
  {
    int nls = t >> 7, j = t & 127;
    int g = (n0 + nls) * Mm + j;
    float lv = bf2f(lpib[g]) + bf2f(lpib[NM + g]) + bf2f(lpib[2 * NM + g]) +
               bf2f(lpib[3 * NM + g]) + alpha0[j];
    lpil[nls * Mm + j] = lv;
    elpi[nls * ELS + j] = __expf(lv);
  }
  if (t < 8) yl[t] = yg[n0 + t];
  __syncthreads();

  // eyelLUT: coalesced global beta read (L2-hot), f32 exact
  {
    int nl2 = t >> 7, j = t & 127;
    float b = betag[yl[nl2] * Mm + j];
    eyelLUT[nl2 * ELS + j] = __expf(2.0f * b) * elpi[nl2 * ELS + j];
  }

  // quad mapping: chain cl = t>>2, slice hq = t&3
  const int cl = t >> 2;
  const int hq = t & 3;
  const int nl = cl >> 5;                 // wave-uniform
  const int s = cl & 31;
  const uint32_t chain = (uint32_t)((n0 + nl) * Ss + s);

  // ---- Z0: lane draws word hq of chain cl ----
  uint32_t zz = 0;
  {
    #pragma unroll 1
    for (int b5 = 0; b5 < 32; ++b5) {
      int mloc = (b5 + hq * 8) & 31;
      int m = hq * 32 + mloc;
      float u = urand(chain, (uint32_t)m);
      float el = elpi[nl * ELS + m];
      zz |= (u * (1.0f + el) < el) ? (1u << mloc) : 0u;
    }
  }

  // ---- init lin = Z0 . beta via MFMA (MFMA roles: chain = L&15, window hw = L>>4) ----
  f32x4 acc[7];
  #pragma unroll
  for (int T = 0; T < 7; ++T) acc[T] = (f32x4){0.f, 0.f, 0.f, 0.f};
  {
    const int liw = L & 15, hw = L >> 4;
    #pragma unroll
    for (int ks = 0; ks < 4; ++ks) {
      uint32_t zw = (uint32_t)__shfl((int)zz, (liw << 2) | ks, 64);
      uint32_t bits8 = (zw >> (hw * 8)) & 0xFFu;
      uint4 pk;
      {
        uint32_t p0 = ((bits8 >> 0) & 1u) ? 0x3F80u : 0xBF80u;
        uint32_t p1 = ((bits8 >> 1) & 1u) ? 0x3F80u : 0xBF80u;
        uint32_t p2 = ((bits8 >> 2) & 1u) ? 0x3F80u : 0xBF80u;
        uint32_t p3 = ((bits8 >> 3) & 1u) ? 0x3F80u : 0xBF80u;
        uint32_t p4 = ((bits8 >> 4) & 1u) ? 0x3F80u : 0xBF80u;
        uint32_t p5 = ((bits8 >> 5) & 1u) ? 0x3F80u : 0xBF80u;
        uint32_t p6 = ((bits8 >> 6) & 1u) ? 0x3F80u : 0xBF80u;
        uint32_t p7 = ((bits8 >> 7) & 1u) ? 0x3F80u : 0xBF80u;
        pk.x = p0 | (p1 << 16); pk.y = p2 | (p3 << 16);
        pk.z = p4 | (p5 << 16); pk.w = p6 | (p7 << 16);
      }
      bf8 B = __builtin_bit_cast(bf8, pk);
      #pragma unroll
      for (int T = 0; T < 7; ++T) {
        int row = T * 16 + liw;
        int kk = ks * 4 + hw;
        bf8 A = __builtin_bit_cast(bf8, *(const uint4*)&bsb[row * 128 + (kk ^ (row & 15)) * 8]);
        acc[T] = __builtin_amdgcn_mfma_f32_16x16x32_bf16(A, B, acc[T], 0, 0, 0);
      }
    }
  }

  // ---- E = exp(lin + beta0)*2^-6 packed f16 (MFMA layout), then quad shuffle ----
  const __half2 HZERO = __builtin_bit_cast(__half2, 0u);
  __half2 E2_0, E2_1, E2_2, E2_3, E2_4, E2_5, E2_6, E2_7;
  __half2 E2_8, E2_9, E2_10, E2_11, E2_12, E2_13;
  {
    int c0m = (L >> 4) * 32;
    MKE(0) MKE(1) MKE(2) MKE(3) MKE(4) MKE(5) MKE(6)
    MKE(7) MKE(8) MKE(9) MKE(10) MKE(11) MKE(12) MKE(13)
    if ((L >> 4) != 0) { E2_12 = HZERO; E2_13 = HZERO; }  // classes >= 100
  }
  {
    int src = (L >> 2) | ((L & 3) << 4);
    SHF(0) SHF(1) SHF(2) SHF(3) SHF(4) SHF(5) SHF(6)
    SHF(7) SHF(8) SHF(9) SHF(10) SHF(11) SHF(12) SHF(13)
  }
  uint32_t zw0 = (uint32_t)__shfl((int)zz, (L & ~3) | 0, 64);
  uint32_t zw1 = (uint32_t)__shfl((int)zz, (L & ~3) | 1, 64);
  uint32_t zw2 = (uint32_t)__shfl((int)zz, (L & ~3) | 2, 64);
  uint32_t zw3 = (uint32_t)__shfl((int)zz, (L & ~3) | 3, 64);

  const uint32_t ONE2 = 0x3C003C00u;   // (1.0h, 1.0h)
  float Sb;
  {
    float d0_ = d2(E2_0, ONE2, 0.f), d1_ = d2(E2_1, ONE2, 0.f);
    float d2_ = d2(E2_2, ONE2, 0.f), d3_ = d2(E2_3, ONE2, 0.f);
    d0_ = d2(E2_4, ONE2, d0_); d1_ = d2(E2_5, ONE2, d1_);
    d2_ = d2(E2_6, ONE2, d2_); d3_ = d2(E2_7, ONE2, d3_);
    d0_ = d2(E2_8, ONE2, d0_); d1_ = d2(E2_9, ONE2, d1_);
    d2_ = d2(E2_10, ONE2, d2_); d3_ = d2(E2_11, ONE2, d3_);
    d0_ = d2(E2_12, ONE2, d0_); d1_ = d2(E2_13, ONE2, d1_);
    Sb = qsum4((d0_ + d1_) + (d2_ + d3_));
  }

  // ---- phase B: rebuild LDS as f16 tables, permuted+chunk-rotated positions ----
  __syncthreads();
  for (int idx = t; idx < 32 * Cc; idx += 1024) {
    int j4 = idx / Cc;
    int c = idx - j4 * Cc;
    int ps = swz(cperm(c));
    float4 bv = *(const float4*)&betag[c * Mm + j4 * 4];
    int j = j4 * 4;
    tab[(j + 0) * SCP + ps] = __float2half(__expf(2.0f * bv.x));
    tab[TOFF + (j + 0) * SCP + ps] = __float2half(__expf(-2.0f * bv.x));
    tab[(j + 1) * SCP + ps] = __float2half(__expf(2.0f * bv.y));
    tab[TOFF + (j + 1) * SCP + ps] = __float2half(__expf(-2.0f * bv.y));
    tab[(j + 2) * SCP + ps] = __float2half(__expf(2.0f * bv.z));
    tab[TOFF + (j + 2) * SCP + ps] = __float2half(__expf(-2.0f * bv.z));
    tab[(j + 3) * SCP + ps] = __float2half(__expf(2.0f * bv.w));
    tab[TOFF + (j + 3) * SCP + ps] = __float2half(__expf(-2.0f * bv.w));
  }
  for (int idx = t; idx < Mm * 28; idx += 1024) {
    int j = idx / 28;
    int c = Cc + (idx - j * 28);
    int ps = swz(cperm(c));
    tab[j * SCP + ps] = __float2half(1.0f);
    tab[TOFF + j * SCP + ps] = __float2half(1.0f);
  }
  for (int idx = t; idx < Mm * 16; idx += 1024) {
    int j = idx >> 4;
    int win = (idx >> 2) & 3, o = 28 + (idx & 3);
    int ps = win * 32 + (((o >> 3) + win) & 3) * 8 + (o & 7);
    tab[j * SCP + ps] = __float2half(1.0f);
    tab[TOFF + j * SCP + ps] = __float2half(1.0f);
  }
  __syncthreads();

  // ---- Gibbs sweep: pair-level ping-pong, depth-2/3 static prefetch ----
  const int rot0 = ((0 + hq) & 3) * 8;
  const int rot1 = ((1 + hq) & 3) * 8;
  const int rot2 = ((2 + hq) & 3) * 8;
  const int rot3 = ((3 + hq) & 3) * 8;

  uint4 sA00, sA01, sA02, sA10, sA11, sA12;
  uint2 sA03, sA13;
  uint4 sB00, sB01, sB02, sB10, sB11, sB12;
  uint2 sB03, sB13;

  PF(sA00, sA01, sA02, sA03, zw0 & 1u, 0)
  PF(sA10, sA11, sA12, sA13, (zw0 >> 1) & 1u, 1)
  float4 eycur = *(const float4*)&eyelLUT[nl * ELS];

  #pragma unroll
  for (int w = 0; w < 4; ++w) {
    uint32_t zwv = (w == 0) ? zw0 : ((w == 1) ? zw1 : ((w == 2) ? zw2 : zw3));
    const uint32_t nextw = (w == 0) ? zw1 : ((w == 1) ? zw2 : ((w == 2) ? zw3 : 0u));
    #pragma unroll 1
    for (int g = 0; g < 8; ++g) {
      const int jb = w * 32 + g * 4;
      const int sh = g * 4;
      uint64_t win = (zwv >> sh) | ((uint64_t)nextw << (32 - sh));
      uint32_t b0 = (uint32_t)win & 1u;
      uint32_t b1 = ((uint32_t)(win >> 1)) & 1u;
      uint32_t b2 = ((uint32_t)(win >> 2)) & 1u;
      uint32_t b3 = ((uint32_t)(win >> 3)) & 1u;
      uint32_t c4 = ((uint32_t)(win >> 4)) & 1u;
      uint32_t c5 = ((uint32_t)(win >> 5)) & 1u;
      uint32_t h1 = hash32(chain, 256u + (uint32_t)jb);
      uint32_t h2 = hash32(chain, 258u + (uint32_t)jb);
      float u0 = (float)(h1 & 0xFFFFu) * (1.0f / 65536.0f);
      float u1 = (float)(h1 >> 16) * (1.0f / 65536.0f);
      float u2 = (float)(h2 & 0xFFFFu) * (1.0f / 65536.0f);
      float u3 = (float)(h2 >> 16) * (1.0f / 65536.0f);
      float um10 = 1.0f - u0, um11 = 1.0f - u1;
      float um12 = 1.0f - u2, um13 = 1.0f - u3;

      PF(sB00, sB01, sB02, sB03, b2, jb + 2)
      PF(sB10, sB11, sB12, sB13, b3, jb + 3)
      __builtin_amdgcn_sched_barrier(0);
      STEP(sA00, sA01, sA02, sA03, b0, eycur.x, u0, um10, b0)
      STEP(sA10, sA11, sA12, sA13, b1, eycur.y, u1, um11, b1)
      PF(sA00, sA01, sA02, sA03, c4, (jb + 4) & 127)
      PF(sA10, sA11, sA12, sA13, c5, (jb + 5) & 127)
      float4 eyn = *(const float4*)&eyelLUT[nl * ELS + ((jb + 4) & 127)];
      __builtin_amdgcn_sched_barrier(0);
      STEP(sB00, sB01, sB02, sB03, b2, eycur.z, u2, um12, b2)
      STEP(sB10, sB11, sB12, sB13, b3, eycur.w, u3, um13, b3)
      eycur = eyn;

      uint32_t nib = b0 | (b1 << 1) | (b2 << 2) | (b3 << 3);
      zwv = (zwv & ~(0xFu << sh)) | (nib << sh);
    }
    if (w == 0) zw0 = zwv; else if (w == 1) zw1 = zwv;
    else if (w == 2) zw2 = zwv; else zw3 = zwv;
  }

  // ---- outputs to LDS ----
  float Sf;
  {
    float d0_ = d2(E2_0, ONE2, 0.f), d1_ = d2(E2_1, ONE2, 0.f);
    float d2_ = d2(E2_2, ONE2, 0.f), d3_ = d2(E2_3, ONE2, 0.f);
    d0_ = d2(E2_4, ONE2, d0_); d1_ = d2(E2_5, ONE2, d1_);
    d2_ = d2(E2_6, ONE2, d2_); d3_ = d2(E2_7, ONE2, d3_);
    d0_ = d2(E2_8, ONE2, d0_); d1_ = d2(E2_9, ONE2, d1_);
    d2_ = d2(E2_10, ONE2, d2_); d3_ = d2(E2_11, ONE2, d3_);
    d0_ = d2(E2_12, ONE2, d0_); d1_ = d2(E2_13, ONE2, d1_);
    Sf = qsum4((d0_ + d1_) + (d2_ + d3_));
  }
  if (hq == 0) {
    lsel[cl] = __logf(Sf) + ESCLOG;
    zsl[cl * 4 + 0] = zw0; zsl[cl * 4 + 1] = zw1;
    zsl[cl * 4 + 2] = zw2; zsl[cl * 4 + 3] = zw3;
  }
  __syncthreads();

  // ---- fused final: moments + all four terms for this block's 8 n-rows ----
  {
    int nl2 = t >> 7;
    int mp = t & 127;
    int wsel = mp >> 5, sh0 = mp & 31;
    int cnt = 0;
    #pragma unroll 1
    for (int s2 = 0; s2 < 32; ++s2)
      cnt += (int)((zsl[(nl2 * 32 + s2) * 4 + wsel] >> sh0) & 1u);
    float EI = (float)cnt * (1.0f / 32.0f);
    float EII = 2.0f * EI - 1.0f;
    float l = lpil[nl2 * Mm + mp];
    int yv2 = yl[nl2];
    float bb = betag[yv2 * Mm + mp];
    float sp = (l > 20.0f) ? l : __logf(1.0f + __expf(l));
    float term = EII * bb + EI * l - sp;
    if (t < 256) term -= lsel[t] * (1.0f / 32.0f);
    if (t < 8) term += beta0g[yl[t]];
    red[t] = term;
  }
  __syncthreads();
  for (int off = 512; off > 0; off >>= 1) {
    if (t < off) red[t] += red[t + off];
    __syncthreads();
  }
  if (t == 0) atomicAdd(out, red[0]);
}

extern "C" void kernel_launch(void* const* d_in, const int* in_sizes, int n_in,
                              void* d_out, int out_size, void* d_ws, size_t ws_size,
                              hipStream_t stream) {
  const float* x = (const float*)d_in[0];
  const int* y = (const int*)d_in[1];
  const float* alpha0 = (const float*)d_in[2];
  const float* alpha = (const float*)d_in[3];
  const float* beta0 = (const float*)d_in[4];
  const float* beta = (const float*)d_in[5];
  float* out = (float*)d_out;

  uint16_t* lpib = (uint16_t*)d_ws;   // 4 bf16 split-K planes = 2 MB

  hipMemsetAsync(d_out, 0, sizeof(float), stream);
  k_lingemm<<<256, 256, 0, stream>>>(x, alpha, lpib);
  k_gibbs<<<256, 1024, 0, stream>>>(beta0, beta, y, alpha0, lpib, out);
}